// Round 5
// baseline (546.364 us; speedup 1.0000x reference)
//
#include <hip/hip_runtime.h>
#include <hip/hip_bf16.h>
#include <math.h>

// GATConv (mode='mul', att='edge') on MI355X
#define NN 50000
#define EE 800000
#define IN_F 128
#define NH 4
#define OUTD 16
#define EMB 32
#define EF 8
#define QK (NH*EMB)      // 128
#define FT (NH*OUTD)     // 64
#define QKROW 256        // packed bf16 row: q dims 0..127, k dims 128..255

__device__ __forceinline__ unsigned short f2bf(float x) {
    unsigned int u = __float_as_uint(x);
    u += 0x7fffu + ((u >> 16) & 1u);   // round-to-nearest-even
    return (unsigned short)(u >> 16);
}
__device__ __forceinline__ float bf2f(unsigned int hi16) {
    return __uint_as_float(hi16 << 16);
}

// ------- fused projection: qk_bf16[n][256], ft_bf16[n][64] from feat -------
#define NPB 32
__global__ __launch_bounds__(320) void proj_kernel(const float* __restrict__ feat,
                                                   const float* __restrict__ Wq,
                                                   const float* __restrict__ Wk,
                                                   const float* __restrict__ Wv,
                                                   unsigned short* __restrict__ qkh,
                                                   unsigned short* __restrict__ fth,
                                                   int n) {
    __shared__ float fs[NPB][IN_F];
    int node0 = blockIdx.x * NPB;
    int tid = threadIdx.x;  // 0..319
    for (int i = tid; i < NPB * IN_F; i += 320) {
        int nn = i >> 7, kk = i & 127;
        int g = node0 + nn;
        fs[nn][kk] = (g < n) ? feat[g * IN_F + kk] : 0.0f;
    }
    __syncthreads();

    int c = tid;  // output column 0..319
    const float* W; int col; int ldw;
    if (c < 128)      { W = Wq; col = c;       ldw = 128; }
    else if (c < 256) { W = Wk; col = c - 128; ldw = 128; }
    else              { W = Wv; col = c - 256; ldw = 64;  }

    float acc[NPB];
#pragma unroll
    for (int i = 0; i < NPB; i++) acc[i] = 0.0f;

    for (int k = 0; k < IN_F; k += 4) {
        float w0 = W[(k + 0) * ldw + col];
        float w1 = W[(k + 1) * ldw + col];
        float w2 = W[(k + 2) * ldw + col];
        float w3 = W[(k + 3) * ldw + col];
#pragma unroll
        for (int i = 0; i < NPB; i++) {
            float4 f = *(const float4*)&fs[i][k];
            acc[i] = fmaf(f.x, w0, fmaf(f.y, w1, fmaf(f.z, w2, fmaf(f.w, w3, acc[i]))));
        }
    }
    for (int i = 0; i < NPB; i++) {
        int g = node0 + i;
        if (g >= n) break;
        unsigned short v = f2bf(acc[i]);
        if (c < 256) qkh[(size_t)g * QKROW + c] = v;
        else         fth[(size_t)g * FT + (c - 256)] = v;
    }
}

// ---------------- CSR build: zero, histogram, scan, perm-fill ---------------
__global__ __launch_bounds__(256) void zero_kernel(int* __restrict__ cnt, int n) {
    int i = blockIdx.x * 256 + threadIdx.x;
    if (i < n) cnt[i] = 0;
}

__global__ __launch_bounds__(256) void hist_kernel(const int* __restrict__ dst,
                                                   int* __restrict__ cnt, int nE) {
    for (int e = blockIdx.x * 256 + threadIdx.x; e < nE; e += gridDim.x * 256)
        atomicAdd(&cnt[dst[e]], 1);
}

// single block, 1024 threads: exclusive scan of cnt[0..n) -> rowptr, cursor
__global__ __launch_bounds__(1024) void scan_kernel(const int* __restrict__ cnt,
                                                    int* __restrict__ rowptr,
                                                    int* __restrict__ cursor, int n) {
    __shared__ int part[1024];
    int tid = threadIdx.x;
    int per = (n + 1023) / 1024;
    int base = tid * per;
    int hi = min(base + per, n);
    int sum = 0;
    for (int i = base; i < hi; i++) sum += cnt[i];
    part[tid] = sum;
    __syncthreads();
    for (int off = 1; off < 1024; off <<= 1) {
        int v = (tid >= off) ? part[tid - off] : 0;
        __syncthreads();
        part[tid] += v;
        __syncthreads();
    }
    int prefix = (tid == 0) ? 0 : part[tid - 1];
    for (int i = base; i < hi; i++) {
        rowptr[i] = prefix;
        cursor[i] = prefix;
        prefix += cnt[i];
    }
    if (tid == 1023) rowptr[n] = part[1023];
}

__global__ __launch_bounds__(256) void perm_kernel(const int* __restrict__ dst,
                                                   int* __restrict__ cursor,
                                                   int* __restrict__ perm, int nE) {
    for (int e = blockIdx.x * 256 + threadIdx.x; e < nE; e += gridDim.x * 256) {
        int pos = atomicAdd(&cursor[dst[e]], 1);
        perm[pos] = e;
    }
}

// ---- edge pass: e[e][h] = sum_d q[s]d * k[t]d * ek_d (no atomics now) -----
__global__ __launch_bounds__(256) void edge_e_kernel(const unsigned int* __restrict__ qk32,
                                                     const float* __restrict__ bond,
                                                     const int* __restrict__ src,
                                                     const int* __restrict__ dst,
                                                     const float* __restrict__ Wek,
                                                     const float* __restrict__ bek,
                                                     float* __restrict__ e_out,
                                                     int nE) {
    int gw = (blockIdx.x * 256 + threadIdx.x) >> 6;
    int lane = threadIdx.x & 63;
    int nw = (gridDim.x * 256) >> 6;
    int d0 = 2 * lane;            // dims d0, d0+1
    int h = lane >> 4;

    float wek0[EF], wek1[EF];
#pragma unroll
    for (int f = 0; f < EF; f++) {
        wek0[f] = Wek[f * QK + d0];
        wek1[f] = Wek[f * QK + d0 + 1];
    }
    float bk0 = bek[d0], bk1 = bek[d0 + 1];

    for (int e = gw; e < nE; e += nw) {
        int s = src[e], t = dst[e];
        float b[EF];
#pragma unroll
        for (int f = 0; f < EF; f++) b[f] = bond[e * EF + f];

        unsigned int qv = qk32[(size_t)s * 128 + lane];
        unsigned int kv = qk32[(size_t)t * 128 + 64 + lane];
        float q0 = bf2f(qv & 0xffffu), q1 = bf2f(qv >> 16);
        float k0 = bf2f(kv & 0xffffu), k1 = bf2f(kv >> 16);

        float ek0 = bk0, ek1 = bk1;
#pragma unroll
        for (int f = 0; f < EF; f++) {
            ek0 = fmaf(b[f], wek0[f], ek0);
            ek1 = fmaf(b[f], wek1[f], ek1);
        }
        float p = fmaf(q0 * k0, ek0, q1 * k1 * ek1);
#pragma unroll
        for (int off = 8; off >= 1; off >>= 1)
            p += __shfl_xor(p, off);
        if ((lane & 15) == 0) e_out[e * NH + h] = p;
    }
}

// ---- per-node fused softmax + weighted aggregate (wave per node) -----------
__global__ __launch_bounds__(256) void agg_kernel(const int* __restrict__ rowptr,
                                                  const int* __restrict__ perm,
                                                  const int* __restrict__ src,
                                                  const float* __restrict__ e_ws,
                                                  const unsigned short* __restrict__ fth,
                                                  const float* __restrict__ bond,
                                                  const float* __restrict__ Wef,
                                                  const float* __restrict__ bef,
                                                  const float* __restrict__ bias,
                                                  float* __restrict__ out, int n) {
    int node = blockIdx.x * 4 + (threadIdx.x >> 6);
    if (node >= n) return;
    int lane = threadIdx.x & 63;
    int h = lane >> 4;            // head for phase 2 (lane = h*16 + o)

    int start = rowptr[node];
    int cnt = rowptr[node + 1] - start;

    // ---- phase 1: per-head max & exp-sum, 16 edge-slots in parallel ----
    int hh = lane & 3;            // head for phase 1 (lane = slot*4 + hh)
    int slot = lane >> 2;
    float m = -INFINITY;
    for (int i = slot; i < cnt; i += 16) {
        int eid = perm[start + i];
        m = fmaxf(m, e_ws[eid * NH + hh]);
    }
#pragma unroll
    for (int off = 4; off < 64; off <<= 1) m = fmaxf(m, __shfl_xor(m, off));

    float s = 0.0f;
    for (int i = slot; i < cnt; i += 16) {
        int eid = perm[start + i];
        s += expf(e_ws[eid * NH + hh] - m);
    }
#pragma unroll
    for (int off = 4; off < 64; off <<= 1) s += __shfl_xor(s, off);

    // lane j (j<4) now holds head-j (m,s); broadcast to phase-2 layout
    float m_h = __shfl(m, h);
    float inv_s = 1.0f / __shfl(s, h);

    // ---- phase 2: accumulate ft[src] * edge_feat * a over edges ----
    float wef[EF];
#pragma unroll
    for (int f = 0; f < EF; f++) wef[f] = Wef[f * FT + lane];
    float be = bef[lane];

    float acc = 0.0f;
    for (int i = 0; i < cnt; i++) {
        int eid = perm[start + i];
        int sN = src[eid];
        float a = expf(e_ws[eid * NH + h] - m_h) * inv_s;
        float4 b0 = *(const float4*)&bond[eid * EF];
        float4 b1 = *(const float4*)&bond[eid * EF + 4];
        float ef = be;
        ef = fmaf(b0.x, wef[0], ef); ef = fmaf(b0.y, wef[1], ef);
        ef = fmaf(b0.z, wef[2], ef); ef = fmaf(b0.w, wef[3], ef);
        ef = fmaf(b1.x, wef[4], ef); ef = fmaf(b1.y, wef[5], ef);
        ef = fmaf(b1.z, wef[6], ef); ef = fmaf(b1.w, wef[7], ef);
        float ftv = bf2f((unsigned int)fth[(size_t)sN * FT + lane]);
        acc = fmaf(ftv * ef, a, acc);
    }
    out[(size_t)node * FT + lane] = acc + bias[lane];
}

extern "C" void kernel_launch(void* const* d_in, const int* in_sizes, int n_in,
                              void* d_out, int out_size, void* d_ws, size_t ws_size,
                              hipStream_t stream) {
    const float* feat = (const float*)d_in[0];
    const float* bond = (const float*)d_in[1];
    const int*   src  = (const int*)d_in[2];
    const int*   dst  = (const int*)d_in[3];
    const float* Wq   = (const float*)d_in[4];
    const float* Wk   = (const float*)d_in[5];
    const float* Wv   = (const float*)d_in[6];
    const float* Wek  = (const float*)d_in[7];
    const float* bek  = (const float*)d_in[8];
    const float* Wef  = (const float*)d_in[9];
    const float* bef  = (const float*)d_in[10];
    const float* bias = (const float*)d_in[11];
    float* out = (float*)d_out;

    const int n = in_sizes[0] / IN_F;   // 50000
    const int nE = in_sizes[2];         // 800000

    // workspace layout
    unsigned int* qk32 = (unsigned int*)d_ws;                        // n*128 u32
    unsigned short* fth = (unsigned short*)(qk32 + (size_t)n * 128); // n*64 u16
    float* e_ws  = (float*)(fth + (size_t)n * FT);                   // nE*4 f32
    int*   cnt    = (int*)(e_ws + (size_t)nE * NH);                  // n
    int*   rowptr = cnt + n;                                         // n+1
    int*   cursor = rowptr + n + 1;                                  // n
    int*   perm   = cursor + n;                                      // nE

    proj_kernel<<<(n + NPB - 1) / NPB, 320, 0, stream>>>(
        feat, Wq, Wk, Wv, (unsigned short*)qk32, fth, n);
    zero_kernel<<<(n + 255) / 256, 256, 0, stream>>>(cnt, n);
    hist_kernel<<<2048, 256, 0, stream>>>(dst, cnt, nE);
    scan_kernel<<<1, 1024, 0, stream>>>(cnt, rowptr, cursor, n);
    perm_kernel<<<2048, 256, 0, stream>>>(dst, cursor, perm, nE);
    edge_e_kernel<<<8192, 256, 0, stream>>>(qk32, bond, src, dst, Wek, bek, e_ws, nE);
    agg_kernel<<<(n + 3) / 4, 256, 0, stream>>>(rowptr, perm, src, e_ws, fth, bond,
                                                Wef, bef, bias, out, n);
}

// Round 6
// 446.978 us; speedup vs baseline: 1.2224x; 1.2224x over previous
//
#include <hip/hip_runtime.h>
#include <hip/hip_bf16.h>
#include <math.h>

// GATConv (mode='mul', att='edge') on MI355X
#define IN_F 128
#define NH 4
#define OUTD 16
#define EMB 32
#define EF 8
#define QK 128           // NH*EMB
#define FT 64            // NH*OUTD
#define QKROW 256        // packed bf16 node row: q dims 0..127, k dims 128..255
#define CAP 128          // per-node LDS exp cache (degree fallback recomputes)

__device__ __forceinline__ unsigned short f2bf(float x) {
    unsigned int u = __float_as_uint(x);
    u += 0x7fffu + ((u >> 16) & 1u);   // round-to-nearest-even
    return (unsigned short)(u >> 16);
}
__device__ __forceinline__ float bf2f(unsigned int hi16) {
    return __uint_as_float(hi16 << 16);
}

// ------- fused projection: qk_bf16[n][256], ft_bf16[n][64] from feat -------
#define NPB 32
__global__ __launch_bounds__(320) void proj_kernel(const float* __restrict__ feat,
                                                   const float* __restrict__ Wq,
                                                   const float* __restrict__ Wk,
                                                   const float* __restrict__ Wv,
                                                   unsigned short* __restrict__ qkh,
                                                   unsigned short* __restrict__ fth,
                                                   int n) {
    __shared__ float fs[NPB][IN_F];
    int node0 = blockIdx.x * NPB;
    int tid = threadIdx.x;  // 0..319
    for (int i = tid; i < NPB * IN_F; i += 320) {
        int nn = i >> 7, kk = i & 127;
        int g = node0 + nn;
        fs[nn][kk] = (g < n) ? feat[g * IN_F + kk] : 0.0f;
    }
    __syncthreads();

    int c = tid;
    const float* W; int col; int ldw;
    if (c < 128)      { W = Wq; col = c;       ldw = 128; }
    else if (c < 256) { W = Wk; col = c - 128; ldw = 128; }
    else              { W = Wv; col = c - 256; ldw = 64;  }

    float acc[NPB];
#pragma unroll
    for (int i = 0; i < NPB; i++) acc[i] = 0.0f;

    for (int k = 0; k < IN_F; k += 4) {
        float w0 = W[(k + 0) * ldw + col];
        float w1 = W[(k + 1) * ldw + col];
        float w2 = W[(k + 2) * ldw + col];
        float w3 = W[(k + 3) * ldw + col];
#pragma unroll
        for (int i = 0; i < NPB; i++) {
            float4 f = *(const float4*)&fs[i][k];
            acc[i] = fmaf(f.x, w0, fmaf(f.y, w1, fmaf(f.z, w2, fmaf(f.w, w3, acc[i]))));
        }
    }
    for (int i = 0; i < NPB; i++) {
        int g = node0 + i;
        if (g >= n) break;
        unsigned short v = f2bf(acc[i]);
        if (c < 256) qkh[(size_t)g * QKROW + c] = v;
        else         fth[(size_t)g * FT + (c - 256)] = v;
    }
}

// ---------------- CSR build ----------------
__global__ __launch_bounds__(256) void hist_kernel(const int* __restrict__ dst,
                                                   int* __restrict__ cnt, int nE) {
    int e = blockIdx.x * 256 + threadIdx.x;
    if (e < nE) atomicAdd(&cnt[dst[e]], 1);
}

// level-1: per-block sums of cnt
__global__ __launch_bounds__(256) void scanA_kernel(const int* __restrict__ cnt,
                                                    int* __restrict__ blocksum, int n) {
    __shared__ int sm[256];
    int tid = threadIdx.x;
    int i = blockIdx.x * 256 + tid;
    sm[tid] = (i < n) ? cnt[i] : 0;
    __syncthreads();
    for (int s = 128; s > 0; s >>= 1) {
        if (tid < s) sm[tid] += sm[tid + s];
        __syncthreads();
    }
    if (tid == 0) blocksum[blockIdx.x] = sm[0];
}

// level-2: single block scans <=256 block sums -> blockoff; writes rowptr[n]=total
__global__ __launch_bounds__(256) void scanB_kernel(const int* __restrict__ blocksum,
                                                    int* __restrict__ blockoff,
                                                    int* __restrict__ rowptr,
                                                    int nb, int n) {
    __shared__ int sm[256];
    int tid = threadIdx.x;
    int v = (tid < nb) ? blocksum[tid] : 0;
    sm[tid] = v;
    __syncthreads();
    for (int off = 1; off < 256; off <<= 1) {
        int t = (tid >= off) ? sm[tid - off] : 0;
        __syncthreads();
        sm[tid] += t;
        __syncthreads();
    }
    blockoff[tid] = sm[tid] - v;        // exclusive
    if (tid == 255) rowptr[n] = sm[255];
}

// level-3: per-block exclusive scan + base -> rowptr, cursor
__global__ __launch_bounds__(256) void scanC_kernel(const int* __restrict__ cnt,
                                                    const int* __restrict__ blockoff,
                                                    int* __restrict__ rowptr,
                                                    int* __restrict__ cursor, int n) {
    __shared__ int sm[256];
    int tid = threadIdx.x;
    int i = blockIdx.x * 256 + tid;
    int v = (i < n) ? cnt[i] : 0;
    sm[tid] = v;
    __syncthreads();
    for (int off = 1; off < 256; off <<= 1) {
        int t = (tid >= off) ? sm[tid - off] : 0;
        __syncthreads();
        sm[tid] += t;
        __syncthreads();
    }
    if (i < n) {
        int r = blockoff[blockIdx.x] + sm[tid] - v;
        rowptr[i] = r;
        cursor[i] = r;
    }
}

// scatter edges into CSR order, materializing srcs and bond_s (kills indirection)
__global__ __launch_bounds__(256) void perm_kernel(const int* __restrict__ src,
                                                   const int* __restrict__ dst,
                                                   const float* __restrict__ bond,
                                                   int* __restrict__ cursor,
                                                   int* __restrict__ srcs,
                                                   float* __restrict__ bond_s, int nE) {
    int e = blockIdx.x * 256 + threadIdx.x;
    if (e >= nE) return;
    int pos = atomicAdd(&cursor[dst[e]], 1);
    srcs[pos] = src[e];
    float4 b0 = *(const float4*)&bond[(size_t)e * EF];
    float4 b1 = *(const float4*)&bond[(size_t)e * EF + 4];
    *(float4*)&bond_s[(size_t)pos * EF] = b0;
    *(float4*)&bond_s[(size_t)pos * EF + 4] = b1;
}

// ---- fused per-node kernel: e-compute + softmax (no max; shift-invariant) +
// ---- weighted aggregate. One node per 256-thread block (4 waves).
__global__ __launch_bounds__(256) void agg_kernel(const int* __restrict__ rowptr,
                                                  const int* __restrict__ srcs,
                                                  const float* __restrict__ bond_s,
                                                  const unsigned int* __restrict__ qk32,
                                                  const unsigned short* __restrict__ fth,
                                                  const float* __restrict__ Wek,
                                                  const float* __restrict__ bek,
                                                  const float* __restrict__ Wef,
                                                  const float* __restrict__ bef,
                                                  const float* __restrict__ bias,
                                                  float* __restrict__ out, int n) {
    __shared__ float pexp[CAP][NH];
    __shared__ float red[4][FT];
    __shared__ float sred[16];

    int node = blockIdx.x;
    int tid = threadIdx.x;
    int lane = tid & 63;
    int w = tid >> 6;
    int h = lane >> 4;          // head (dims d0,d0+1 are in head lane>>4; also output head)
    int d0 = 2 * lane;

    int start = rowptr[node];
    int cnt = rowptr[node + 1] - start;

    // loop-invariant: Wek fragment, k[node]
    float wek0[EF], wek1[EF];
#pragma unroll
    for (int f = 0; f < EF; f++) {
        wek0[f] = Wek[f * QK + d0];
        wek1[f] = Wek[f * QK + d0 + 1];
    }
    float bk0 = bek[d0], bk1 = bek[d0 + 1];
    unsigned int kv = qk32[(size_t)node * 128 + 64 + lane];
    float k0 = bf2f(kv & 0xffffu), k1 = bf2f(kv >> 16);

    // ---- phase A: e + exp, cache in LDS, per-head sum ----
    float s_loc = 0.0f;
    for (int i = w; i < cnt; i += 4) {
        int idx = start + i;
        int sN = srcs[idx];
        unsigned int qv = qk32[(size_t)sN * 128 + lane];
        float4 b0 = *(const float4*)&bond_s[(size_t)idx * EF];
        float4 b1 = *(const float4*)&bond_s[(size_t)idx * EF + 4];
        float q0 = bf2f(qv & 0xffffu), q1 = bf2f(qv >> 16);
        float ek0 = bk0, ek1 = bk1;
        ek0 = fmaf(b0.x, wek0[0], ek0); ek1 = fmaf(b0.x, wek1[0], ek1);
        ek0 = fmaf(b0.y, wek0[1], ek0); ek1 = fmaf(b0.y, wek1[1], ek1);
        ek0 = fmaf(b0.z, wek0[2], ek0); ek1 = fmaf(b0.z, wek1[2], ek1);
        ek0 = fmaf(b0.w, wek0[3], ek0); ek1 = fmaf(b0.w, wek1[3], ek1);
        ek0 = fmaf(b1.x, wek0[4], ek0); ek1 = fmaf(b1.x, wek1[4], ek1);
        ek0 = fmaf(b1.y, wek0[5], ek0); ek1 = fmaf(b1.y, wek1[5], ek1);
        ek0 = fmaf(b1.z, wek0[6], ek0); ek1 = fmaf(b1.z, wek1[6], ek1);
        ek0 = fmaf(b1.w, wek0[7], ek0); ek1 = fmaf(b1.w, wek1[7], ek1);
        float p = fmaf(q0 * k0, ek0, q1 * k1 * ek1);
#pragma unroll
        for (int off = 8; off >= 1; off >>= 1) p += __shfl_xor(p, off);
        float ex = expf(p);
        if ((lane & 15) == 0) {
            if (i < CAP) pexp[i][h] = ex;
            s_loc += ex;
        }
    }
    if ((lane & 15) == 0) sred[w * 4 + h] = s_loc;
    __syncthreads();
    float inv_s = 1.0f / (sred[h] + sred[4 + h] + sred[8 + h] + sred[12 + h]);

    // ---- phase B: accumulate ft[src] * edge_feat * a ----
    float wef[EF];
#pragma unroll
    for (int f = 0; f < EF; f++) wef[f] = Wef[f * FT + lane];
    float be = bef[lane];

    float acc = 0.0f;
    for (int i = w; i < cnt; i += 4) {
        int idx = start + i;
        int sN = srcs[idx];
        float4 b0 = *(const float4*)&bond_s[(size_t)idx * EF];
        float4 b1 = *(const float4*)&bond_s[(size_t)idx * EF + 4];
        float ex;
        if (i < CAP) {
            ex = pexp[i][h];
        } else {  // degree > CAP fallback: recompute (wave-uniform branch)
            unsigned int qv = qk32[(size_t)sN * 128 + lane];
            float q0 = bf2f(qv & 0xffffu), q1 = bf2f(qv >> 16);
            float ek0 = bk0, ek1 = bk1;
            ek0 = fmaf(b0.x, wek0[0], ek0); ek1 = fmaf(b0.x, wek1[0], ek1);
            ek0 = fmaf(b0.y, wek0[1], ek0); ek1 = fmaf(b0.y, wek1[1], ek1);
            ek0 = fmaf(b0.z, wek0[2], ek0); ek1 = fmaf(b0.z, wek1[2], ek1);
            ek0 = fmaf(b0.w, wek0[3], ek0); ek1 = fmaf(b0.w, wek1[3], ek1);
            ek0 = fmaf(b1.x, wek0[4], ek0); ek1 = fmaf(b1.x, wek1[4], ek1);
            ek0 = fmaf(b1.y, wek0[5], ek0); ek1 = fmaf(b1.y, wek1[5], ek1);
            ek0 = fmaf(b1.z, wek0[6], ek0); ek1 = fmaf(b1.z, wek1[6], ek1);
            ek0 = fmaf(b1.w, wek0[7], ek0); ek1 = fmaf(b1.w, wek1[7], ek1);
            float p = fmaf(q0 * k0, ek0, q1 * k1 * ek1);
#pragma unroll
            for (int off = 8; off >= 1; off >>= 1) p += __shfl_xor(p, off);
            ex = expf(p);
        }
        float a = ex * inv_s;
        float ef = be;
        ef = fmaf(b0.x, wef[0], ef); ef = fmaf(b0.y, wef[1], ef);
        ef = fmaf(b0.z, wef[2], ef); ef = fmaf(b0.w, wef[3], ef);
        ef = fmaf(b1.x, wef[4], ef); ef = fmaf(b1.y, wef[5], ef);
        ef = fmaf(b1.z, wef[6], ef); ef = fmaf(b1.w, wef[7], ef);
        float ftv = bf2f((unsigned int)fth[(size_t)sN * FT + lane]);
        acc = fmaf(ftv * ef, a, acc);
    }
    red[w][lane] = acc;
    __syncthreads();
    if (tid < FT) {
        out[(size_t)node * FT + tid] =
            red[0][tid] + red[1][tid] + red[2][tid] + red[3][tid] + bias[tid];
    }
}

extern "C" void kernel_launch(void* const* d_in, const int* in_sizes, int n_in,
                              void* d_out, int out_size, void* d_ws, size_t ws_size,
                              hipStream_t stream) {
    const float* feat = (const float*)d_in[0];
    const float* bond = (const float*)d_in[1];
    const int*   src  = (const int*)d_in[2];
    const int*   dst  = (const int*)d_in[3];
    const float* Wq   = (const float*)d_in[4];
    const float* Wk   = (const float*)d_in[5];
    const float* Wv   = (const float*)d_in[6];
    const float* Wek  = (const float*)d_in[7];
    const float* bek  = (const float*)d_in[8];
    const float* Wef  = (const float*)d_in[9];
    const float* bef  = (const float*)d_in[10];
    const float* bias = (const float*)d_in[11];
    float* out = (float*)d_out;

    const int n = in_sizes[0] / IN_F;   // 50000
    const int nE = in_sizes[2];         // 800000
    const int NB = (n + 255) / 256;     // 196 (must be <= 256 for scanB)

    // workspace layout (16B-aligned segments)
    unsigned int* qk32 = (unsigned int*)d_ws;                         // n*128 u32
    unsigned short* fth = (unsigned short*)(qk32 + (size_t)n * 128);  // n*64 u16
    int*   srcs   = (int*)(fth + (size_t)n * FT);                     // nE
    float* bond_s = (float*)(srcs + (size_t)nE);                      // nE*8
    int*   cnt      = (int*)(bond_s + (size_t)nE * EF);               // n
    int*   rowptr   = cnt + n;                                        // n+1
    int*   cursor   = rowptr + n + 1;                                 // n
    int*   blocksum = cursor + n;                                     // NB
    int*   blockoff = blocksum + 256;                                 // 256

    hipMemsetAsync(cnt, 0, (size_t)n * sizeof(int), stream);
    proj_kernel<<<(n + NPB - 1) / NPB, 320, 0, stream>>>(
        feat, Wq, Wk, Wv, (unsigned short*)qk32, fth, n);
    hist_kernel<<<(nE + 255) / 256, 256, 0, stream>>>(dst, cnt, nE);
    scanA_kernel<<<NB, 256, 0, stream>>>(cnt, blocksum, n);
    scanB_kernel<<<1, 256, 0, stream>>>(blocksum, blockoff, rowptr, NB, n);
    scanC_kernel<<<NB, 256, 0, stream>>>(cnt, blockoff, rowptr, cursor, n);
    perm_kernel<<<(nE + 255) / 256, 256, 0, stream>>>(src, dst, bond, cursor,
                                                      srcs, bond_s, nE);
    agg_kernel<<<n, 256, 0, stream>>>(rowptr, srcs, bond_s, qk32, fth,
                                      Wek, bek, Wef, bef, bias, out, n);
}

// Round 7
// 331.433 us; speedup vs baseline: 1.6485x; 1.3486x over previous
//
#include <hip/hip_runtime.h>
#include <hip/hip_bf16.h>
#include <math.h>

// GATConv (mode='mul', att='edge') on MI355X
#define IN_F 128
#define NH 4
#define OUTD 16
#define EMB 32
#define EF 8
#define QK 128           // NH*EMB
#define FT 64            // NH*OUTD
#define QKROW 256        // packed bf16 node row: q dims 0..127, k dims 128..255

__device__ __forceinline__ unsigned short f2bf(float x) {
    unsigned int u = __float_as_uint(x);
    u += 0x7fffu + ((u >> 16) & 1u);   // round-to-nearest-even
    return (unsigned short)(u >> 16);
}
__device__ __forceinline__ float bf2f(unsigned int hi16) {
    return __uint_as_float(hi16 << 16);
}

// ------- fused projection: qk_bf16[n][256], ft_bf16[n][64] from feat -------
#define NPB 32
__global__ __launch_bounds__(320) void proj_kernel(const float* __restrict__ feat,
                                                   const float* __restrict__ Wq,
                                                   const float* __restrict__ Wk,
                                                   const float* __restrict__ Wv,
                                                   unsigned short* __restrict__ qkh,
                                                   unsigned short* __restrict__ fth,
                                                   int n) {
    __shared__ float fs[NPB][IN_F];
    int node0 = blockIdx.x * NPB;
    int tid = threadIdx.x;  // 0..319
    for (int i = tid; i < NPB * IN_F; i += 320) {
        int nn = i >> 7, kk = i & 127;
        int g = node0 + nn;
        fs[nn][kk] = (g < n) ? feat[g * IN_F + kk] : 0.0f;
    }
    __syncthreads();

    int c = tid;
    const float* W; int col; int ldw;
    if (c < 128)      { W = Wq; col = c;       ldw = 128; }
    else if (c < 256) { W = Wk; col = c - 128; ldw = 128; }
    else              { W = Wv; col = c - 256; ldw = 64;  }

    float acc[NPB];
#pragma unroll
    for (int i = 0; i < NPB; i++) acc[i] = 0.0f;

    for (int k = 0; k < IN_F; k += 4) {
        float w0 = W[(k + 0) * ldw + col];
        float w1 = W[(k + 1) * ldw + col];
        float w2 = W[(k + 2) * ldw + col];
        float w3 = W[(k + 3) * ldw + col];
#pragma unroll
        for (int i = 0; i < NPB; i++) {
            float4 f = *(const float4*)&fs[i][k];
            acc[i] = fmaf(f.x, w0, fmaf(f.y, w1, fmaf(f.z, w2, fmaf(f.w, w3, acc[i]))));
        }
    }
    for (int i = 0; i < NPB; i++) {
        int g = node0 + i;
        if (g >= n) break;
        unsigned short v = f2bf(acc[i]);
        if (c < 256) qkh[(size_t)g * QKROW + c] = v;
        else         fth[(size_t)g * FT + (c - 256)] = v;
    }
}

// ---------------- CSR build ----------------
__global__ __launch_bounds__(256) void hist_kernel(const int* __restrict__ dst,
                                                   int* __restrict__ cnt, int nE) {
    int e = blockIdx.x * 256 + threadIdx.x;
    if (e < nE) atomicAdd(&cnt[dst[e]], 1);
}

__global__ __launch_bounds__(256) void scanA_kernel(const int* __restrict__ cnt,
                                                    int* __restrict__ blocksum, int n) {
    __shared__ int sm[256];
    int tid = threadIdx.x;
    int i = blockIdx.x * 256 + tid;
    sm[tid] = (i < n) ? cnt[i] : 0;
    __syncthreads();
    for (int s = 128; s > 0; s >>= 1) {
        if (tid < s) sm[tid] += sm[tid + s];
        __syncthreads();
    }
    if (tid == 0) blocksum[blockIdx.x] = sm[0];
}

__global__ __launch_bounds__(256) void scanB_kernel(const int* __restrict__ blocksum,
                                                    int* __restrict__ blockoff,
                                                    int* __restrict__ rowptr,
                                                    int nb, int n) {
    __shared__ int sm[256];
    int tid = threadIdx.x;
    int v = (tid < nb) ? blocksum[tid] : 0;
    sm[tid] = v;
    __syncthreads();
    for (int off = 1; off < 256; off <<= 1) {
        int t = (tid >= off) ? sm[tid - off] : 0;
        __syncthreads();
        sm[tid] += t;
        __syncthreads();
    }
    blockoff[tid] = sm[tid] - v;        // exclusive
    if (tid == 255) rowptr[n] = sm[255];
}

__global__ __launch_bounds__(256) void scanC_kernel(const int* __restrict__ cnt,
                                                    const int* __restrict__ blockoff,
                                                    int* __restrict__ rowptr,
                                                    int* __restrict__ cursor, int n) {
    __shared__ int sm[256];
    int tid = threadIdx.x;
    int i = blockIdx.x * 256 + tid;
    int v = (i < n) ? cnt[i] : 0;
    sm[tid] = v;
    __syncthreads();
    for (int off = 1; off < 256; off <<= 1) {
        int t = (tid >= off) ? sm[tid - off] : 0;
        __syncthreads();
        sm[tid] += t;
        __syncthreads();
    }
    if (i < n) {
        int r = blockoff[blockIdx.x] + sm[tid] - v;
        rowptr[i] = r;
        cursor[i] = r;
    }
}

// scatter edges into CSR order, materializing srcs and bond_s
__global__ __launch_bounds__(256) void perm_kernel(const int* __restrict__ src,
                                                   const int* __restrict__ dst,
                                                   const float* __restrict__ bond,
                                                   int* __restrict__ cursor,
                                                   int* __restrict__ srcs,
                                                   float* __restrict__ bond_s, int nE) {
    int e = blockIdx.x * 256 + threadIdx.x;
    if (e >= nE) return;
    int pos = atomicAdd(&cursor[dst[e]], 1);
    srcs[pos] = src[e];
    float4 b0 = *(const float4*)&bond[(size_t)e * EF];
    float4 b1 = *(const float4*)&bond[(size_t)e * EF + 4];
    *(float4*)&bond_s[(size_t)pos * EF] = b0;
    *(float4*)&bond_s[(size_t)pos * EF + 4] = b1;
}

// ---- fused single-pass per-node kernel --------------------------------------
// out[node] = (sum_e exp(e_e) * ft[src_e] (.) ef_e) / (sum_e exp(e_e)) + bias
// One node per 256-thread block (4 waves); lane = h*16 + o; dims (2*lane, 2*lane+1).
__global__ __launch_bounds__(256) void agg_kernel(const int* __restrict__ rowptr,
                                                  const int* __restrict__ srcs,
                                                  const float* __restrict__ bond_s,
                                                  const unsigned int* __restrict__ qk32,
                                                  const unsigned short* __restrict__ fth,
                                                  const float* __restrict__ Wek,
                                                  const float* __restrict__ bek,
                                                  const float* __restrict__ Wef,
                                                  const float* __restrict__ bef,
                                                  const float* __restrict__ bias,
                                                  float* __restrict__ out, int n) {
    __shared__ float red[4][FT];
    __shared__ float sred[16];

    int node = blockIdx.x;
    int tid = threadIdx.x;
    int lane = tid & 63;
    int w = tid >> 6;
    int d0 = 2 * lane;

    int start = rowptr[node];
    int cnt = rowptr[node + 1] - start;

    // loop invariants: Wek/Wef fragments, k[node] dims (d0,d0+1)
    float wek0[EF], wek1[EF], wef[EF];
#pragma unroll
    for (int f = 0; f < EF; f++) {
        wek0[f] = Wek[f * QK + d0];
        wek1[f] = Wek[f * QK + d0 + 1];
        wef[f] = Wef[f * FT + lane];
    }
    float bk0 = bek[d0], bk1 = bek[d0 + 1];
    float be = bef[lane];
    unsigned int kv = qk32[(size_t)node * 128 + 64 + lane];
    float k0 = bf2f(kv & 0xffffu), k1 = bf2f(kv >> 16);

    // prefetch this node's src indices (cnt <= 64 in one coalesced load)
    int sN_all = (lane < cnt) ? srcs[start + lane] : 0;

    float acc = 0.0f, s_loc = 0.0f;
    for (int i = w; i < cnt; i += 4) {
        int idx = start + i;
        int sN = (i < 64) ? __shfl(sN_all, i) : srcs[idx];
        // two independent gathers, issued together
        unsigned int qv = qk32[(size_t)sN * 128 + lane];
        float ftv = bf2f((unsigned int)fth[(size_t)sN * FT + lane]);
        // sequential (L1-friendly) bond reads, wave-uniform
        float4 b0 = *(const float4*)&bond_s[(size_t)idx * EF];
        float4 b1 = *(const float4*)&bond_s[(size_t)idx * EF + 4];

        float q0 = bf2f(qv & 0xffffu), q1 = bf2f(qv >> 16);
        float ek0 = bk0, ek1 = bk1;
        ek0 = fmaf(b0.x, wek0[0], ek0); ek1 = fmaf(b0.x, wek1[0], ek1);
        ek0 = fmaf(b0.y, wek0[1], ek0); ek1 = fmaf(b0.y, wek1[1], ek1);
        ek0 = fmaf(b0.z, wek0[2], ek0); ek1 = fmaf(b0.z, wek1[2], ek1);
        ek0 = fmaf(b0.w, wek0[3], ek0); ek1 = fmaf(b0.w, wek1[3], ek1);
        ek0 = fmaf(b1.x, wek0[4], ek0); ek1 = fmaf(b1.x, wek1[4], ek1);
        ek0 = fmaf(b1.y, wek0[5], ek0); ek1 = fmaf(b1.y, wek1[5], ek1);
        ek0 = fmaf(b1.z, wek0[6], ek0); ek1 = fmaf(b1.z, wek1[6], ek1);
        ek0 = fmaf(b1.w, wek0[7], ek0); ek1 = fmaf(b1.w, wek1[7], ek1);
        float p = fmaf(q0 * k0, ek0, q1 * k1 * ek1);
        // reduce over the 16-lane head group -> every lane holds e for head lane>>4
#pragma unroll
        for (int off = 8; off >= 1; off >>= 1) p += __shfl_xor(p, off);
        float ex = expf(p);

        float ef = be;
        ef = fmaf(b0.x, wef[0], ef); ef = fmaf(b0.y, wef[1], ef);
        ef = fmaf(b0.z, wef[2], ef); ef = fmaf(b0.w, wef[3], ef);
        ef = fmaf(b1.x, wef[4], ef); ef = fmaf(b1.y, wef[5], ef);
        ef = fmaf(b1.z, wef[6], ef); ef = fmaf(b1.w, wef[7], ef);

        acc = fmaf(ex * ftv, ef, acc);   // unnormalized
        s_loc += ex;
    }

    red[w][lane] = acc;
    if ((lane & 15) == 0) sred[w * 4 + (lane >> 4)] = s_loc;
    __syncthreads();

    if (tid < FT) {
        int ho = tid >> 4;
        float stot = sred[ho] + sred[4 + ho] + sred[8 + ho] + sred[12 + ho];
        float inv = (cnt > 0) ? 1.0f / stot : 0.0f;
        out[(size_t)node * FT + tid] =
            (red[0][tid] + red[1][tid] + red[2][tid] + red[3][tid]) * inv + bias[tid];
    }
}

extern "C" void kernel_launch(void* const* d_in, const int* in_sizes, int n_in,
                              void* d_out, int out_size, void* d_ws, size_t ws_size,
                              hipStream_t stream) {
    const float* feat = (const float*)d_in[0];
    const float* bond = (const float*)d_in[1];
    const int*   src  = (const int*)d_in[2];
    const int*   dst  = (const int*)d_in[3];
    const float* Wq   = (const float*)d_in[4];
    const float* Wk   = (const float*)d_in[5];
    const float* Wv   = (const float*)d_in[6];
    const float* Wek  = (const float*)d_in[7];
    const float* bek  = (const float*)d_in[8];
    const float* Wef  = (const float*)d_in[9];
    const float* bef  = (const float*)d_in[10];
    const float* bias = (const float*)d_in[11];
    float* out = (float*)d_out;

    const int n = in_sizes[0] / IN_F;   // 50000
    const int nE = in_sizes[2];         // 800000
    const int NB = (n + 255) / 256;     // 196 (<=256 for scanB)

    // workspace layout
    unsigned int* qk32 = (unsigned int*)d_ws;                         // n*128 u32
    unsigned short* fth = (unsigned short*)(qk32 + (size_t)n * 128);  // n*64 u16
    int*   srcs   = (int*)(fth + (size_t)n * FT);                     // nE
    float* bond_s = (float*)(srcs + (size_t)nE);                      // nE*8
    int*   cnt      = (int*)(bond_s + (size_t)nE * EF);               // n
    int*   rowptr   = cnt + n;                                        // n+1
    int*   cursor   = rowptr + n + 1;                                 // n
    int*   blocksum = cursor + n;                                     // 256
    int*   blockoff = blocksum + 256;                                 // 256

    hipMemsetAsync(cnt, 0, (size_t)n * sizeof(int), stream);
    proj_kernel<<<(n + NPB - 1) / NPB, 320, 0, stream>>>(
        feat, Wq, Wk, Wv, (unsigned short*)qk32, fth, n);
    hist_kernel<<<(nE + 255) / 256, 256, 0, stream>>>(dst, cnt, nE);
    scanA_kernel<<<NB, 256, 0, stream>>>(cnt, blocksum, n);
    scanB_kernel<<<1, 256, 0, stream>>>(blocksum, blockoff, rowptr, NB, n);
    scanC_kernel<<<NB, 256, 0, stream>>>(cnt, blockoff, rowptr, cursor, n);
    perm_kernel<<<(nE + 255) / 256, 256, 0, stream>>>(src, dst, bond, cursor,
                                                      srcs, bond_s, nE);
    agg_kernel<<<n, 256, 0, stream>>>(rowptr, srcs, bond_s, qk32, fth,
                                      Wek, bek, Wef, bef, bias, out, n);
}

// Round 8
// 294.204 us; speedup vs baseline: 1.8571x; 1.1265x over previous
//
#include <hip/hip_runtime.h>
#include <hip/hip_bf16.h>
#include <math.h>

// GATConv (mode='mul', att='edge') on MI355X
#define IN_F 128
#define NH 4
#define OUTD 16
#define EMB 32
#define EF 8
#define QK 128           // NH*EMB
#define FT 64            // NH*OUTD
#define QKROW 256        // packed bf16 node row: q dims 0..127, k dims 128..255

__device__ __forceinline__ unsigned short f2bf(float x) {
    unsigned int u = __float_as_uint(x);
    u += 0x7fffu + ((u >> 16) & 1u);   // round-to-nearest-even
    return (unsigned short)(u >> 16);
}
__device__ __forceinline__ float bf2f(unsigned int hi16) {
    return __uint_as_float(hi16 << 16);
}

// ------- fused projection: qk_bf16[n][256], ft_bf16[n][64] from feat -------
#define NPB 32
__global__ __launch_bounds__(320) void proj_kernel(const float* __restrict__ feat,
                                                   const float* __restrict__ Wq,
                                                   const float* __restrict__ Wk,
                                                   const float* __restrict__ Wv,
                                                   unsigned short* __restrict__ qkh,
                                                   unsigned short* __restrict__ fth,
                                                   int n) {
    __shared__ float fs[NPB][IN_F];
    int node0 = blockIdx.x * NPB;
    int tid = threadIdx.x;  // 0..319
    for (int i = tid; i < NPB * IN_F; i += 320) {
        int nn = i >> 7, kk = i & 127;
        int g = node0 + nn;
        fs[nn][kk] = (g < n) ? feat[g * IN_F + kk] : 0.0f;
    }
    __syncthreads();

    int c = tid;
    const float* W; int col; int ldw;
    if (c < 128)      { W = Wq; col = c;       ldw = 128; }
    else if (c < 256) { W = Wk; col = c - 128; ldw = 128; }
    else              { W = Wv; col = c - 256; ldw = 64;  }

    float acc[NPB];
#pragma unroll
    for (int i = 0; i < NPB; i++) acc[i] = 0.0f;

    for (int k = 0; k < IN_F; k += 4) {
        float w0 = W[(k + 0) * ldw + col];
        float w1 = W[(k + 1) * ldw + col];
        float w2 = W[(k + 2) * ldw + col];
        float w3 = W[(k + 3) * ldw + col];
#pragma unroll
        for (int i = 0; i < NPB; i++) {
            float4 f = *(const float4*)&fs[i][k];
            acc[i] = fmaf(f.x, w0, fmaf(f.y, w1, fmaf(f.z, w2, fmaf(f.w, w3, acc[i]))));
        }
    }
    for (int i = 0; i < NPB; i++) {
        int g = node0 + i;
        if (g >= n) break;
        unsigned short v = f2bf(acc[i]);
        if (c < 256) qkh[(size_t)g * QKROW + c] = v;
        else         fth[(size_t)g * FT + (c - 256)] = v;
    }
}

// ---------------- CSR build ----------------
__global__ __launch_bounds__(256) void hist_kernel(const int* __restrict__ dst,
                                                   int* __restrict__ cnt, int nE) {
    int e = blockIdx.x * 256 + threadIdx.x;
    if (e < nE) atomicAdd(&cnt[dst[e]], 1);
}

__global__ __launch_bounds__(256) void scanA_kernel(const int* __restrict__ cnt,
                                                    int* __restrict__ blocksum, int n) {
    __shared__ int sm[256];
    int tid = threadIdx.x;
    int i = blockIdx.x * 256 + tid;
    sm[tid] = (i < n) ? cnt[i] : 0;
    __syncthreads();
    for (int s = 128; s > 0; s >>= 1) {
        if (tid < s) sm[tid] += sm[tid + s];
        __syncthreads();
    }
    if (tid == 0) blocksum[blockIdx.x] = sm[0];
}

__global__ __launch_bounds__(256) void scanB_kernel(const int* __restrict__ blocksum,
                                                    int* __restrict__ blockoff,
                                                    int* __restrict__ rowptr,
                                                    int nb, int n) {
    __shared__ int sm[256];
    int tid = threadIdx.x;
    int v = (tid < nb) ? blocksum[tid] : 0;
    sm[tid] = v;
    __syncthreads();
    for (int off = 1; off < 256; off <<= 1) {
        int t = (tid >= off) ? sm[tid - off] : 0;
        __syncthreads();
        sm[tid] += t;
        __syncthreads();
    }
    blockoff[tid] = sm[tid] - v;        // exclusive
    if (tid == 255) rowptr[n] = sm[255];
}

__global__ __launch_bounds__(256) void scanC_kernel(const int* __restrict__ cnt,
                                                    const int* __restrict__ blockoff,
                                                    int* __restrict__ rowptr,
                                                    int* __restrict__ cursor, int n) {
    __shared__ int sm[256];
    int tid = threadIdx.x;
    int i = blockIdx.x * 256 + tid;
    int v = (i < n) ? cnt[i] : 0;
    sm[tid] = v;
    __syncthreads();
    for (int off = 1; off < 256; off <<= 1) {
        int t = (tid >= off) ? sm[tid - off] : 0;
        __syncthreads();
        sm[tid] += t;
        __syncthreads();
    }
    if (i < n) {
        int r = blockoff[blockIdx.x] + sm[tid] - v;
        rowptr[i] = r;
        cursor[i] = r;
    }
}

// scatter edges into CSR order, materializing srcs and bond_s
__global__ __launch_bounds__(256) void perm_kernel(const int* __restrict__ src,
                                                   const int* __restrict__ dst,
                                                   const float* __restrict__ bond,
                                                   int* __restrict__ cursor,
                                                   int* __restrict__ srcs,
                                                   float* __restrict__ bond_s, int nE) {
    int e = blockIdx.x * 256 + threadIdx.x;
    if (e >= nE) return;
    int pos = atomicAdd(&cursor[dst[e]], 1);
    srcs[pos] = src[e];
    float4 b0 = *(const float4*)&bond[(size_t)e * EF];
    float4 b1 = *(const float4*)&bond[(size_t)e * EF + 4];
    *(float4*)&bond_s[(size_t)pos * EF] = b0;
    *(float4*)&bond_s[(size_t)pos * EF + 4] = b1;
}

// ---- fused single-pass aggregate: persistent wave-per-node, no LDS ---------
// out[node] = (sum_e exp(e_e) * ft[src_e] (.) ef_e) / (sum_e exp(e_e)) + bias
// lane = h*16 + o ; dims (2*lane, 2*lane+1) belong to head lane>>4.
__global__ __launch_bounds__(256) void agg_kernel(const int* __restrict__ rowptr,
                                                  const int* __restrict__ srcs,
                                                  const float* __restrict__ bond_s,
                                                  const unsigned int* __restrict__ qk32,
                                                  const unsigned short* __restrict__ fth,
                                                  const float* __restrict__ Wek,
                                                  const float* __restrict__ bek,
                                                  const float* __restrict__ Wef,
                                                  const float* __restrict__ bef,
                                                  const float* __restrict__ bias,
                                                  float* __restrict__ out, int n) {
    int lane = threadIdx.x & 63;
    int gw = (blockIdx.x * 256 + threadIdx.x) >> 6;
    int nw = (gridDim.x * 256) >> 6;
    int d0 = 2 * lane;

    // wave-lifetime invariants
    float wek0[EF], wek1[EF], wef[EF];
#pragma unroll
    for (int f = 0; f < EF; f++) {
        wek0[f] = Wek[f * QK + d0];
        wek1[f] = Wek[f * QK + d0 + 1];
        wef[f]  = Wef[f * FT + lane];
    }
    float bk0 = bek[d0], bk1 = bek[d0 + 1];
    float be = bef[lane];
    float bias_l = bias[lane];

    for (int node = gw; node < n; node += nw) {
        int start = __builtin_amdgcn_readfirstlane(rowptr[node]);
        int cnt   = __builtin_amdgcn_readfirstlane(rowptr[node + 1]) - start;

        unsigned int kv = qk32[node * 128 + 64 + lane];
        float k0 = bf2f(kv & 0xffffu), k1 = bf2f(kv >> 16);
        // prefetch src indices (degree <= 64 in one coalesced load; rare tail reloads)
        int sN_all = (lane < cnt) ? srcs[start + lane] : 0;

        float acc = 0.0f, s_loc = 0.0f;
        for (int i = 0; i < cnt; i++) {
            int sN = (i < 64) ? __shfl(sN_all, i) : srcs[start + i];
            // two independent gathers on the same index, issued back-to-back
            unsigned int qv = qk32[sN * 128 + lane];
            float ftv = bf2f((unsigned int)fth[sN * 64 + lane]);
            int bidx = (start + i) * EF;          // wave-uniform
            float4 b0 = *(const float4*)&bond_s[bidx];
            float4 b1 = *(const float4*)&bond_s[bidx + 4];

            float q0 = bf2f(qv & 0xffffu), q1 = bf2f(qv >> 16);
            float ek0 = bk0, ek1 = bk1;
            ek0 = fmaf(b0.x, wek0[0], ek0); ek1 = fmaf(b0.x, wek1[0], ek1);
            ek0 = fmaf(b0.y, wek0[1], ek0); ek1 = fmaf(b0.y, wek1[1], ek1);
            ek0 = fmaf(b0.z, wek0[2], ek0); ek1 = fmaf(b0.z, wek1[2], ek1);
            ek0 = fmaf(b0.w, wek0[3], ek0); ek1 = fmaf(b0.w, wek1[3], ek1);
            ek0 = fmaf(b1.x, wek0[4], ek0); ek1 = fmaf(b1.x, wek1[4], ek1);
            ek0 = fmaf(b1.y, wek0[5], ek0); ek1 = fmaf(b1.y, wek1[5], ek1);
            ek0 = fmaf(b1.z, wek0[6], ek0); ek1 = fmaf(b1.z, wek1[6], ek1);
            ek0 = fmaf(b1.w, wek0[7], ek0); ek1 = fmaf(b1.w, wek1[7], ek1);
            float p = fmaf(q0 * k0, ek0, q1 * k1 * ek1);
            // 16-lane head-group reduce: all lanes of the group end with e(head)
#pragma unroll
            for (int off = 8; off >= 1; off >>= 1) p += __shfl_xor(p, off);
            float ex = __expf(p);                 // |p| small; 2-ulp fast exp

            float ef = be;
            ef = fmaf(b0.x, wef[0], ef); ef = fmaf(b0.y, wef[1], ef);
            ef = fmaf(b0.z, wef[2], ef); ef = fmaf(b0.w, wef[3], ef);
            ef = fmaf(b1.x, wef[4], ef); ef = fmaf(b1.y, wef[5], ef);
            ef = fmaf(b1.z, wef[6], ef); ef = fmaf(b1.w, wef[7], ef);

            acc = fmaf(ex * ftv, ef, acc);        // unnormalized accumulate
            s_loc += ex;                          // lane-identical within head group
        }
        float inv = (cnt > 0) ? 1.0f / s_loc : 0.0f;
        out[node * FT + lane] = acc * inv + bias_l;
    }
}

extern "C" void kernel_launch(void* const* d_in, const int* in_sizes, int n_in,
                              void* d_out, int out_size, void* d_ws, size_t ws_size,
                              hipStream_t stream) {
    const float* feat = (const float*)d_in[0];
    const float* bond = (const float*)d_in[1];
    const int*   src  = (const int*)d_in[2];
    const int*   dst  = (const int*)d_in[3];
    const float* Wq   = (const float*)d_in[4];
    const float* Wk   = (const float*)d_in[5];
    const float* Wv   = (const float*)d_in[6];
    const float* Wek  = (const float*)d_in[7];
    const float* bek  = (const float*)d_in[8];
    const float* Wef  = (const float*)d_in[9];
    const float* bef  = (const float*)d_in[10];
    const float* bias = (const float*)d_in[11];
    float* out = (float*)d_out;

    const int n = in_sizes[0] / IN_F;   // 50000
    const int nE = in_sizes[2];         // 800000
    const int NB = (n + 255) / 256;     // 196 (<=256 for scanB)

    // workspace layout
    unsigned int* qk32 = (unsigned int*)d_ws;                         // n*128 u32
    unsigned short* fth = (unsigned short*)(qk32 + (size_t)n * 128);  // n*64 u16
    int*   srcs   = (int*)(fth + (size_t)n * FT);                     // nE
    float* bond_s = (float*)(srcs + (size_t)nE);                      // nE*8
    int*   cnt      = (int*)(bond_s + (size_t)nE * EF);               // n
    int*   rowptr   = cnt + n;                                        // n+1
    int*   cursor   = rowptr + n + 1;                                 // n
    int*   blocksum = cursor + n;                                     // 256
    int*   blockoff = blocksum + 256;                                 // 256

    hipMemsetAsync(cnt, 0, (size_t)n * sizeof(int), stream);
    proj_kernel<<<(n + NPB - 1) / NPB, 320, 0, stream>>>(
        feat, Wq, Wk, Wv, (unsigned short*)qk32, fth, n);
    hist_kernel<<<(nE + 255) / 256, 256, 0, stream>>>(dst, cnt, nE);
    scanA_kernel<<<NB, 256, 0, stream>>>(cnt, blocksum, n);
    scanB_kernel<<<1, 256, 0, stream>>>(blocksum, blockoff, rowptr, NB, n);
    scanC_kernel<<<NB, 256, 0, stream>>>(cnt, blockoff, rowptr, cursor, n);
    perm_kernel<<<(nE + 255) / 256, 256, 0, stream>>>(src, dst, bond, cursor,
                                                      srcs, bond_s, nE);
    agg_kernel<<<2048, 256, 0, stream>>>(rowptr, srcs, bond_s, qk32, fth,
                                         Wek, bek, Wef, bef, bias, out, n);
}

// Round 9
// 242.532 us; speedup vs baseline: 2.2528x; 1.2131x over previous
//
#include <hip/hip_runtime.h>
#include <hip/hip_bf16.h>
#include <math.h>

// GATConv (mode='mul', att='edge') on MI355X
#define IN_F 128
#define NH 4
#define OUTD 16
#define EMB 32
#define EF 8
#define QK 128           // NH*EMB
#define FT 64            // NH*OUTD
#define NCOL 320         // q(128) | k(128) | ft(64)

typedef __attribute__((ext_vector_type(8))) short bf16x8;
typedef __attribute__((ext_vector_type(4))) float f32x4;

__device__ __forceinline__ unsigned short f2bf(float x) {
    unsigned int u = __float_as_uint(x);
    u += 0x7fffu + ((u >> 16) & 1u);   // round-to-nearest-even
    return (unsigned short)(u >> 16);
}
__device__ __forceinline__ float bf2f(unsigned int hi16) {
    return __uint_as_float(hi16 << 16);
}

// ---------------- prep: feat -> bf16 [n][128] (8 elems/thread) -------------
__global__ __launch_bounds__(256) void prepF_kernel(const float* __restrict__ feat,
                                                    unsigned short* __restrict__ featH,
                                                    int total8) {
    int i = blockIdx.x * 256 + threadIdx.x;
    if (i >= total8) return;
    float4 a = ((const float4*)feat)[2 * i];
    float4 b = ((const float4*)feat)[2 * i + 1];
    ushort4 lo, hi;
    lo.x = f2bf(a.x); lo.y = f2bf(a.y); lo.z = f2bf(a.z); lo.w = f2bf(a.w);
    hi.x = f2bf(b.x); hi.y = f2bf(b.y); hi.z = f2bf(b.z); hi.w = f2bf(b.w);
    ((ushort4*)featH)[2 * i] = lo;
    ((ushort4*)featH)[2 * i + 1] = hi;
}

// ------- prep: WT[col][k] bf16, col 0..127=Wq, 128..255=Wk, 256..319=Wv ----
__global__ __launch_bounds__(256) void prepW_kernel(const float* __restrict__ Wq,
                                                    const float* __restrict__ Wk,
                                                    const float* __restrict__ Wv,
                                                    unsigned short* __restrict__ WT) {
    int idx = blockIdx.x * 256 + threadIdx.x;
    if (idx >= NCOL * IN_F) return;
    int k = idx / NCOL, col = idx % NCOL;
    float v;
    if (col < 128)      v = Wq[k * 128 + col];
    else if (col < 256) v = Wk[k * 128 + (col - 128)];
    else                v = Wv[k * 64 + (col - 256)];
    WT[col * IN_F + k] = f2bf(v);
}

// ------- MFMA projection: [n][320] = featH @ [WT^T], outputs bf16 ----------
// block = 4 waves x 16 rows; wave loops 20 N-tiles x 4 K-chunks of 16x16x32.
__global__ __launch_bounds__(256) void mfma_proj_kernel(
        const unsigned short* __restrict__ featH,   // [n][128]
        const unsigned short* __restrict__ WT,      // [320][128]
        unsigned short* __restrict__ qkh,           // [n][256]
        unsigned short* __restrict__ fth,           // [n][64]
        int n) {
    int lane = threadIdx.x & 63;
    int w = threadIdx.x >> 6;
    int rbase = blockIdx.x * 64 + w * 16;
    int arow = rbase + (lane & 15);
    int kg = (lane >> 4) * 8;                 // k-offset within a 32-chunk

    bf16x8 zero = {0, 0, 0, 0, 0, 0, 0, 0};
    bf16x8 afrag[4];
#pragma unroll
    for (int kc = 0; kc < 4; kc++) {
        afrag[kc] = (arow < n)
            ? *(const bf16x8*)&featH[(size_t)arow * IN_F + kc * 32 + kg]
            : zero;
    }

    for (int c = 0; c < 20; c++) {
        int col = c * 16 + (lane & 15);
        f32x4 acc = {0.f, 0.f, 0.f, 0.f};
#pragma unroll
        for (int kc = 0; kc < 4; kc++) {
            bf16x8 bfrag = *(const bf16x8*)&WT[(size_t)col * IN_F + kc * 32 + kg];
            acc = __builtin_amdgcn_mfma_f32_16x16x32_bf16(afrag[kc], bfrag, acc, 0, 0, 0);
        }
#pragma unroll
        for (int r = 0; r < 4; r++) {
            int row = rbase + (lane >> 4) * 4 + r;
            if (row < n) {
                unsigned short v = f2bf(acc[r]);
                if (col < 256) qkh[(size_t)row * 256 + col] = v;
                else           fth[(size_t)row * 64 + (col - 256)] = v;
            }
        }
    }
}

// ---------------- CSR build ----------------
__global__ __launch_bounds__(256) void hist_kernel(const int* __restrict__ dst,
                                                   int* __restrict__ cnt, int nE) {
    int e = blockIdx.x * 256 + threadIdx.x;
    if (e < nE) atomicAdd(&cnt[dst[e]], 1);
}

__global__ __launch_bounds__(256) void scanA_kernel(const int* __restrict__ cnt,
                                                    int* __restrict__ blocksum, int n) {
    __shared__ int sm[256];
    int tid = threadIdx.x;
    int i = blockIdx.x * 256 + tid;
    sm[tid] = (i < n) ? cnt[i] : 0;
    __syncthreads();
    for (int s = 128; s > 0; s >>= 1) {
        if (tid < s) sm[tid] += sm[tid + s];
        __syncthreads();
    }
    if (tid == 0) blocksum[blockIdx.x] = sm[0];
}

__global__ __launch_bounds__(256) void scanB_kernel(const int* __restrict__ blocksum,
                                                    int* __restrict__ blockoff,
                                                    int* __restrict__ rowptr,
                                                    int nb, int n) {
    __shared__ int sm[256];
    int tid = threadIdx.x;
    int v = (tid < nb) ? blocksum[tid] : 0;
    sm[tid] = v;
    __syncthreads();
    for (int off = 1; off < 256; off <<= 1) {
        int t = (tid >= off) ? sm[tid - off] : 0;
        __syncthreads();
        sm[tid] += t;
        __syncthreads();
    }
    blockoff[tid] = sm[tid] - v;        // exclusive
    if (tid == 255) rowptr[n] = sm[255];
}

__global__ __launch_bounds__(256) void scanC_kernel(const int* __restrict__ cnt,
                                                    const int* __restrict__ blockoff,
                                                    int* __restrict__ rowptr,
                                                    int* __restrict__ cursor, int n) {
    __shared__ int sm[256];
    int tid = threadIdx.x;
    int i = blockIdx.x * 256 + tid;
    int v = (i < n) ? cnt[i] : 0;
    sm[tid] = v;
    __syncthreads();
    for (int off = 1; off < 256; off <<= 1) {
        int t = (tid >= off) ? sm[tid - off] : 0;
        __syncthreads();
        sm[tid] += t;
        __syncthreads();
    }
    if (i < n) {
        int r = blockoff[blockIdx.x] + sm[tid] - v;
        rowptr[i] = r;
        cursor[i] = r;
    }
}

// scatter edges into CSR order, materializing srcs and bond_s
__global__ __launch_bounds__(256) void perm_kernel(const int* __restrict__ src,
                                                   const int* __restrict__ dst,
                                                   const float* __restrict__ bond,
                                                   int* __restrict__ cursor,
                                                   int* __restrict__ srcs,
                                                   float* __restrict__ bond_s, int nE) {
    int e = blockIdx.x * 256 + threadIdx.x;
    if (e >= nE) return;
    int pos = atomicAdd(&cursor[dst[e]], 1);
    srcs[pos] = src[e];
    float4 b0 = *(const float4*)&bond[(size_t)e * EF];
    float4 b1 = *(const float4*)&bond[(size_t)e * EF + 4];
    *(float4*)&bond_s[(size_t)pos * EF] = b0;
    *(float4*)&bond_s[(size_t)pos * EF + 4] = b1;
}

// ---- fused single-pass aggregate: persistent wave-per-node, no LDS ---------
// out[node] = (sum_e exp(e_e) * ft[src_e] (.) ef_e) / (sum_e exp(e_e)) + bias
__global__ __launch_bounds__(256) void agg_kernel(const int* __restrict__ rowptr,
                                                  const int* __restrict__ srcs,
                                                  const float* __restrict__ bond_s,
                                                  const unsigned int* __restrict__ qk32,
                                                  const unsigned short* __restrict__ fth,
                                                  const float* __restrict__ Wek,
                                                  const float* __restrict__ bek,
                                                  const float* __restrict__ Wef,
                                                  const float* __restrict__ bef,
                                                  const float* __restrict__ bias,
                                                  float* __restrict__ out, int n) {
    int lane = threadIdx.x & 63;
    int gw = (blockIdx.x * 256 + threadIdx.x) >> 6;
    int nw = (gridDim.x * 256) >> 6;
    int d0 = 2 * lane;

    float wek0[EF], wek1[EF], wef[EF];
#pragma unroll
    for (int f = 0; f < EF; f++) {
        wek0[f] = Wek[f * QK + d0];
        wek1[f] = Wek[f * QK + d0 + 1];
        wef[f]  = Wef[f * FT + lane];
    }
    float bk0 = bek[d0], bk1 = bek[d0 + 1];
    float be = bef[lane];
    float bias_l = bias[lane];

    for (int node = gw; node < n; node += nw) {
        int start = __builtin_amdgcn_readfirstlane(rowptr[node]);
        int cnt   = __builtin_amdgcn_readfirstlane(rowptr[node + 1]) - start;

        unsigned int kv = qk32[node * 128 + 64 + lane];
        float k0 = bf2f(kv & 0xffffu), k1 = bf2f(kv >> 16);
        int sN_all = (lane < cnt) ? srcs[start + lane] : 0;

        float acc = 0.0f, s_loc = 0.0f;
        for (int i = 0; i < cnt; i++) {
            int sN = (i < 64) ? __shfl(sN_all, i) : srcs[start + i];
            unsigned int qv = qk32[sN * 128 + lane];
            float ftv = bf2f((unsigned int)fth[sN * 64 + lane]);
            int bidx = (start + i) * EF;
            float4 b0 = *(const float4*)&bond_s[bidx];
            float4 b1 = *(const float4*)&bond_s[bidx + 4];

            float q0 = bf2f(qv & 0xffffu), q1 = bf2f(qv >> 16);
            float ek0 = bk0, ek1 = bk1;
            ek0 = fmaf(b0.x, wek0[0], ek0); ek1 = fmaf(b0.x, wek1[0], ek1);
            ek0 = fmaf(b0.y, wek0[1], ek0); ek1 = fmaf(b0.y, wek1[1], ek1);
            ek0 = fmaf(b0.z, wek0[2], ek0); ek1 = fmaf(b0.z, wek1[2], ek1);
            ek0 = fmaf(b0.w, wek0[3], ek0); ek1 = fmaf(b0.w, wek1[3], ek1);
            ek0 = fmaf(b1.x, wek0[4], ek0); ek1 = fmaf(b1.x, wek1[4], ek1);
            ek0 = fmaf(b1.y, wek0[5], ek0); ek1 = fmaf(b1.y, wek1[5], ek1);
            ek0 = fmaf(b1.z, wek0[6], ek0); ek1 = fmaf(b1.z, wek1[6], ek1);
            ek0 = fmaf(b1.w, wek0[7], ek0); ek1 = fmaf(b1.w, wek1[7], ek1);
            float p = fmaf(q0 * k0, ek0, q1 * k1 * ek1);
#pragma unroll
            for (int off = 8; off >= 1; off >>= 1) p += __shfl_xor(p, off);
            float ex = __expf(p);

            float ef = be;
            ef = fmaf(b0.x, wef[0], ef); ef = fmaf(b0.y, wef[1], ef);
            ef = fmaf(b0.z, wef[2], ef); ef = fmaf(b0.w, wef[3], ef);
            ef = fmaf(b1.x, wef[4], ef); ef = fmaf(b1.y, wef[5], ef);
            ef = fmaf(b1.z, wef[6], ef); ef = fmaf(b1.w, wef[7], ef);

            acc = fmaf(ex * ftv, ef, acc);
            s_loc += ex;
        }
        float inv = (cnt > 0) ? 1.0f / s_loc : 0.0f;
        out[node * FT + lane] = acc * inv + bias_l;
    }
}

extern "C" void kernel_launch(void* const* d_in, const int* in_sizes, int n_in,
                              void* d_out, int out_size, void* d_ws, size_t ws_size,
                              hipStream_t stream) {
    const float* feat = (const float*)d_in[0];
    const float* bond = (const float*)d_in[1];
    const int*   src  = (const int*)d_in[2];
    const int*   dst  = (const int*)d_in[3];
    const float* Wq   = (const float*)d_in[4];
    const float* Wk   = (const float*)d_in[5];
    const float* Wv   = (const float*)d_in[6];
    const float* Wek  = (const float*)d_in[7];
    const float* bek  = (const float*)d_in[8];
    const float* Wef  = (const float*)d_in[9];
    const float* bef  = (const float*)d_in[10];
    const float* bias = (const float*)d_in[11];
    float* out = (float*)d_out;

    const int n = in_sizes[0] / IN_F;   // 50000
    const int nE = in_sizes[2];         // 800000
    const int NB = (n + 255) / 256;     // 196 (<=256 for scanB)

    // workspace layout
    unsigned int* qk32 = (unsigned int*)d_ws;                         // n*128 u32
    unsigned short* fth = (unsigned short*)(qk32 + (size_t)n * 128);  // n*64 u16
    int*   srcs   = (int*)(fth + (size_t)n * FT);                     // nE
    float* bond_s = (float*)(srcs + (size_t)nE);                      // nE*8
    int*   cnt      = (int*)(bond_s + (size_t)nE * EF);               // n
    int*   rowptr   = cnt + n;                                        // n+1
    int*   cursor   = rowptr + n + 1;                                 // n
    int*   blocksum = cursor + n;                                     // 256
    int*   blockoff = blocksum + 256;                                 // 256
    unsigned short* featH = (unsigned short*)(blockoff + 256);        // n*128 u16
    unsigned short* WT = featH + (size_t)n * IN_F;                    // 320*128 u16

    hipMemsetAsync(cnt, 0, (size_t)n * sizeof(int), stream);
    prepF_kernel<<<(n * IN_F / 8 + 255) / 256, 256, 0, stream>>>(feat, featH, n * IN_F / 8);
    prepW_kernel<<<(NCOL * IN_F + 255) / 256, 256, 0, stream>>>(Wq, Wk, Wv, WT);
    mfma_proj_kernel<<<(n + 63) / 64, 256, 0, stream>>>(
        featH, WT, (unsigned short*)qk32, fth, n);
    hist_kernel<<<(nE + 255) / 256, 256, 0, stream>>>(dst, cnt, nE);
    scanA_kernel<<<NB, 256, 0, stream>>>(cnt, blocksum, n);
    scanB_kernel<<<1, 256, 0, stream>>>(blocksum, blockoff, rowptr, NB, n);
    scanC_kernel<<<NB, 256, 0, stream>>>(cnt, blockoff, rowptr, cursor, n);
    perm_kernel<<<(nE + 255) / 256, 256, 0, stream>>>(src, dst, bond, cursor,
                                                      srcs, bond_s, nE);
    agg_kernel<<<2048, 256, 0, stream>>>(rowptr, srcs, bond_s, qk32, fth,
                                         Wek, bek, Wef, bef, bias, out, n);
}

// Round 10
// 224.110 us; speedup vs baseline: 2.4379x; 1.0822x over previous
//
#include <hip/hip_runtime.h>
#include <hip/hip_bf16.h>
#include <math.h>

// GATConv (mode='mul', att='edge') on MI355X
#define IN_F 128
#define NH 4
#define OUTD 16
#define EMB 32
#define EF 8
#define QK 128           // NH*EMB
#define FT 64            // NH*OUTD
#define NCOL 320         // q(128) | k(128) | ft(64)

typedef __attribute__((ext_vector_type(8))) short bf16x8;
typedef __attribute__((ext_vector_type(4))) float f32x4;
typedef __attribute__((ext_vector_type(2))) float f32x2;

__device__ __forceinline__ unsigned short f2bf(float x) {
    unsigned int u = __float_as_uint(x);
    u += 0x7fffu + ((u >> 16) & 1u);   // round-to-nearest-even
    return (unsigned short)(u >> 16);
}
__device__ __forceinline__ float bf2f(unsigned int hi16) {
    return __uint_as_float(hi16 << 16);
}
__device__ __forceinline__ f32x2 fma2(float s, f32x2 a, f32x2 c) {
    f32x2 sv = {s, s};
    return __builtin_elementwise_fma(sv, a, c);   // v_pk_fma_f32
}

// ---------------- prep: feat -> bf16 [n][128] (8 elems/thread) -------------
__global__ __launch_bounds__(256) void prepF_kernel(const float* __restrict__ feat,
                                                    unsigned short* __restrict__ featH,
                                                    int total8) {
    int i = blockIdx.x * 256 + threadIdx.x;
    if (i >= total8) return;
    float4 a = ((const float4*)feat)[2 * i];
    float4 b = ((const float4*)feat)[2 * i + 1];
    ushort4 lo, hi;
    lo.x = f2bf(a.x); lo.y = f2bf(a.y); lo.z = f2bf(a.z); lo.w = f2bf(a.w);
    hi.x = f2bf(b.x); hi.y = f2bf(b.y); hi.z = f2bf(b.z); hi.w = f2bf(b.w);
    ((ushort4*)featH)[2 * i] = lo;
    ((ushort4*)featH)[2 * i + 1] = hi;
}

// ------- prep: WT[col][k] bf16, col 0..127=Wq, 128..255=Wk, 256..319=Wv ----
__global__ __launch_bounds__(256) void prepW_kernel(const float* __restrict__ Wq,
                                                    const float* __restrict__ Wk,
                                                    const float* __restrict__ Wv,
                                                    unsigned short* __restrict__ WT) {
    int idx = blockIdx.x * 256 + threadIdx.x;
    if (idx >= NCOL * IN_F) return;
    int k = idx / NCOL, col = idx % NCOL;
    float v;
    if (col < 128)      v = Wq[k * 128 + col];
    else if (col < 256) v = Wk[k * 128 + (col - 128)];
    else                v = Wv[k * 64 + (col - 256)];
    WT[col * IN_F + k] = f2bf(v);
}

// ------- MFMA projection: [n][320] = featH @ [WT^T], outputs bf16 ----------
// block = 4 waves x 32 rows; wave: 2 M-tiles share each B-fragment load.
__global__ __launch_bounds__(256) void mfma_proj_kernel(
        const unsigned short* __restrict__ featH,   // [n][128]
        const unsigned short* __restrict__ WT,      // [320][128]
        unsigned short* __restrict__ qkh,           // [n][256]
        unsigned short* __restrict__ fth,           // [n][64]
        int n) {
    int lane = threadIdx.x & 63;
    int w = threadIdx.x >> 6;
    int rbase = blockIdx.x * 128 + w * 32;
    int ar = lane & 15;
    int kg = (lane >> 4) * 8;                 // k-offset within a 32-chunk

    bf16x8 zero = {0, 0, 0, 0, 0, 0, 0, 0};
    bf16x8 afrag[2][4];
#pragma unroll
    for (int t = 0; t < 2; t++) {
        int row = rbase + t * 16 + ar;
#pragma unroll
        for (int kc = 0; kc < 4; kc++) {
            afrag[t][kc] = (row < n)
                ? *(const bf16x8*)&featH[(size_t)row * IN_F + kc * 32 + kg]
                : zero;
        }
    }

    for (int c = 0; c < 20; c++) {
        int col = c * 16 + ar;
        f32x4 acc0 = {0.f, 0.f, 0.f, 0.f};
        f32x4 acc1 = {0.f, 0.f, 0.f, 0.f};
#pragma unroll
        for (int kc = 0; kc < 4; kc++) {
            bf16x8 bfrag = *(const bf16x8*)&WT[(size_t)col * IN_F + kc * 32 + kg];
            acc0 = __builtin_amdgcn_mfma_f32_16x16x32_bf16(afrag[0][kc], bfrag, acc0, 0, 0, 0);
            acc1 = __builtin_amdgcn_mfma_f32_16x16x32_bf16(afrag[1][kc], bfrag, acc1, 0, 0, 0);
        }
#pragma unroll
        for (int t = 0; t < 2; t++) {
            f32x4 acc = (t == 0) ? acc0 : acc1;
#pragma unroll
            for (int r = 0; r < 4; r++) {
                int row = rbase + t * 16 + (lane >> 4) * 4 + r;
                if (row < n) {
                    unsigned short v = f2bf(acc[r]);
                    if (col < 256) qkh[(size_t)row * 256 + col] = v;
                    else           fth[(size_t)row * 64 + (col - 256)] = v;
                }
            }
        }
    }
}

// ---------------- CSR build ----------------
__global__ __launch_bounds__(256) void hist_kernel(const int* __restrict__ dst,
                                                   int* __restrict__ cnt, int nE) {
    int e = blockIdx.x * 256 + threadIdx.x;
    if (e < nE) atomicAdd(&cnt[dst[e]], 1);
}

__global__ __launch_bounds__(256) void scanA_kernel(const int* __restrict__ cnt,
                                                    int* __restrict__ blocksum, int n) {
    __shared__ int sm[256];
    int tid = threadIdx.x;
    int i = blockIdx.x * 256 + tid;
    sm[tid] = (i < n) ? cnt[i] : 0;
    __syncthreads();
    for (int s = 128; s > 0; s >>= 1) {
        if (tid < s) sm[tid] += sm[tid + s];
        __syncthreads();
    }
    if (tid == 0) blocksum[blockIdx.x] = sm[0];
}

__global__ __launch_bounds__(256) void scanB_kernel(const int* __restrict__ blocksum,
                                                    int* __restrict__ blockoff,
                                                    int* __restrict__ rowptr,
                                                    int nb, int n) {
    __shared__ int sm[256];
    int tid = threadIdx.x;
    int v = (tid < nb) ? blocksum[tid] : 0;
    sm[tid] = v;
    __syncthreads();
    for (int off = 1; off < 256; off <<= 1) {
        int t = (tid >= off) ? sm[tid - off] : 0;
        __syncthreads();
        sm[tid] += t;
        __syncthreads();
    }
    blockoff[tid] = sm[tid] - v;        // exclusive
    if (tid == 255) rowptr[n] = sm[255];
}

__global__ __launch_bounds__(256) void scanC_kernel(const int* __restrict__ cnt,
                                                    const int* __restrict__ blockoff,
                                                    int* __restrict__ rowptr,
                                                    int* __restrict__ cursor, int n) {
    __shared__ int sm[256];
    int tid = threadIdx.x;
    int i = blockIdx.x * 256 + tid;
    int v = (i < n) ? cnt[i] : 0;
    sm[tid] = v;
    __syncthreads();
    for (int off = 1; off < 256; off <<= 1) {
        int t = (tid >= off) ? sm[tid - off] : 0;
        __syncthreads();
        sm[tid] += t;
        __syncthreads();
    }
    if (i < n) {
        int r = blockoff[blockIdx.x] + sm[tid] - v;
        rowptr[i] = r;
        cursor[i] = r;
    }
}

// scatter edges into CSR order, materializing srcs and bond_s
__global__ __launch_bounds__(256) void perm_kernel(const int* __restrict__ src,
                                                   const int* __restrict__ dst,
                                                   const float* __restrict__ bond,
                                                   int* __restrict__ cursor,
                                                   int* __restrict__ srcs,
                                                   float* __restrict__ bond_s, int nE) {
    int e = blockIdx.x * 256 + threadIdx.x;
    if (e >= nE) return;
    int pos = atomicAdd(&cursor[dst[e]], 1);
    srcs[pos] = src[e];
    float4 b0 = *(const float4*)&bond[(size_t)e * EF];
    float4 b1 = *(const float4*)&bond[(size_t)e * EF + 4];
    *(float4*)&bond_s[(size_t)pos * EF] = b0;
    *(float4*)&bond_s[(size_t)pos * EF + 4] = b1;
}

// ---- fused single-pass aggregate: persistent wave-per-node ------------------
// out[node] = (sum_e exp(e_e) * ft[src_e] (.) ef_e) / (sum_e exp(e_e)) + bias
// lane = h*16 + o ; dims (2*lane, 2*lane+1) belong to head lane>>4.
// sN pulled to SGPR via readlane -> gather addressing on the SALU pipe.
#define EDGE_BODY(sN, idx, ACC, SL) do {                                   \
    unsigned int qv_ = qk32[(sN) * 128 + lane];                            \
    float ftv_ = bf2f((unsigned int)fth[(sN) * 64 + lane]);                \
    float4 b0_ = *(const float4*)&bond_s[(size_t)(idx) * 8];               \
    float4 b1_ = *(const float4*)&bond_s[(size_t)(idx) * 8 + 4];           \
    f32x2 qf_; qf_.x = __uint_as_float(qv_ << 16);                         \
    qf_.y = __uint_as_float(qv_ & 0xffff0000u);                            \
    f32x2 ek_ = bk;                                                        \
    ek_ = fma2(b0_.x, wek[0], ek_); ek_ = fma2(b0_.y, wek[1], ek_);        \
    ek_ = fma2(b0_.z, wek[2], ek_); ek_ = fma2(b0_.w, wek[3], ek_);        \
    ek_ = fma2(b1_.x, wek[4], ek_); ek_ = fma2(b1_.y, wek[5], ek_);        \
    ek_ = fma2(b1_.z, wek[6], ek_); ek_ = fma2(b1_.w, wek[7], ek_);        \
    f32x2 t_ = qf_ * kf * ek_;                                             \
    float p_ = t_.x + t_.y;                                                \
    p_ += __shfl_xor(p_, 8); p_ += __shfl_xor(p_, 4);                      \
    p_ += __shfl_xor(p_, 2); p_ += __shfl_xor(p_, 1);                      \
    float ex_ = __expf(p_);                                                \
    float ef_ = be;                                                        \
    ef_ = fmaf(b0_.x, wef[0], ef_); ef_ = fmaf(b0_.y, wef[1], ef_);        \
    ef_ = fmaf(b0_.z, wef[2], ef_); ef_ = fmaf(b0_.w, wef[3], ef_);        \
    ef_ = fmaf(b1_.x, wef[4], ef_); ef_ = fmaf(b1_.y, wef[5], ef_);        \
    ef_ = fmaf(b1_.z, wef[6], ef_); ef_ = fmaf(b1_.w, wef[7], ef_);        \
    ACC = fmaf(ex_ * ftv_, ef_, ACC);                                      \
    SL += ex_;                                                             \
} while (0)

__global__ __launch_bounds__(256) void agg_kernel(const int* __restrict__ rowptr,
                                                  const int* __restrict__ srcs,
                                                  const float* __restrict__ bond_s,
                                                  const unsigned int* __restrict__ qk32,
                                                  const unsigned short* __restrict__ fth,
                                                  const float* __restrict__ Wek,
                                                  const float* __restrict__ bek,
                                                  const float* __restrict__ Wef,
                                                  const float* __restrict__ bef,
                                                  const float* __restrict__ bias,
                                                  float* __restrict__ out, int n) {
    int lane = threadIdx.x & 63;
    int gw = (blockIdx.x * 256 + threadIdx.x) >> 6;
    int nw = (gridDim.x * 256) >> 6;
    int d0 = 2 * lane;

    // wave-lifetime invariants
    f32x2 wek[EF];
    float wef[EF];
#pragma unroll
    for (int f = 0; f < EF; f++) {
        wek[f] = *(const f32x2*)&Wek[f * QK + d0];
        wef[f] = Wef[f * FT + lane];
    }
    f32x2 bk = *(const f32x2*)&bek[d0];
    float be = bef[lane];
    float bias_l = bias[lane];

    for (int node = gw; node < n; node += nw) {
        int start = __builtin_amdgcn_readfirstlane(rowptr[node]);
        int cnt   = __builtin_amdgcn_readfirstlane(rowptr[node + 1]) - start;

        unsigned int kv = qk32[node * 128 + 64 + lane];
        f32x2 kf; kf.x = __uint_as_float(kv << 16);
        kf.y = __uint_as_float(kv & 0xffff0000u);

        float accA = 0.0f, accB = 0.0f, slA = 0.0f, slB = 0.0f;
        if (cnt <= 64) {
            int sN_all = (lane < cnt) ? srcs[start + lane] : 0;
            int i = 0;
            for (; i + 2 <= cnt; i += 2) {
                int sA = __builtin_amdgcn_readlane(sN_all, i);
                int sB = __builtin_amdgcn_readlane(sN_all, i + 1);
                EDGE_BODY(sA, start + i, accA, slA);
                EDGE_BODY(sB, start + i + 1, accB, slB);
            }
            if (i < cnt) {
                int sA = __builtin_amdgcn_readlane(sN_all, i);
                EDGE_BODY(sA, start + i, accA, slA);
            }
        } else {
            for (int i = 0; i < cnt; i++) {
                int sA = __builtin_amdgcn_readfirstlane(srcs[start + i]);
                EDGE_BODY(sA, start + i, accA, slA);
            }
        }
        float s_tot = slA + slB;
        float inv = (cnt > 0) ? 1.0f / s_tot : 0.0f;
        out[node * FT + lane] = (accA + accB) * inv + bias_l;
    }
}

extern "C" void kernel_launch(void* const* d_in, const int* in_sizes, int n_in,
                              void* d_out, int out_size, void* d_ws, size_t ws_size,
                              hipStream_t stream) {
    const float* feat = (const float*)d_in[0];
    const float* bond = (const float*)d_in[1];
    const int*   src  = (const int*)d_in[2];
    const int*   dst  = (const int*)d_in[3];
    const float* Wq   = (const float*)d_in[4];
    const float* Wk   = (const float*)d_in[5];
    const float* Wv   = (const float*)d_in[6];
    const float* Wek  = (const float*)d_in[7];
    const float* bek  = (const float*)d_in[8];
    const float* Wef  = (const float*)d_in[9];
    const float* bef  = (const float*)d_in[10];
    const float* bias = (const float*)d_in[11];
    float* out = (float*)d_out;

    const int n = in_sizes[0] / IN_F;   // 50000
    const int nE = in_sizes[2];         // 800000
    const int NB = (n + 255) / 256;     // 196 (<=256 for scanB)

    // workspace layout
    unsigned int* qk32 = (unsigned int*)d_ws;                         // n*128 u32
    unsigned short* fth = (unsigned short*)(qk32 + (size_t)n * 128);  // n*64 u16
    int*   srcs   = (int*)(fth + (size_t)n * FT);                     // nE
    float* bond_s = (float*)(srcs + (size_t)nE);                      // nE*8
    int*   cnt      = (int*)(bond_s + (size_t)nE * EF);               // n
    int*   rowptr   = cnt + n;                                        // n+1
    int*   cursor   = rowptr + n + 1;                                 // n
    int*   blocksum = cursor + n;                                     // 256
    int*   blockoff = blocksum + 256;                                 // 256
    unsigned short* featH = (unsigned short*)(blockoff + 256);        // n*128 u16
    unsigned short* WT = featH + (size_t)n * IN_F;                    // 320*128 u16

    hipMemsetAsync(cnt, 0, (size_t)n * sizeof(int), stream);
    prepF_kernel<<<(n * IN_F / 8 + 255) / 256, 256, 0, stream>>>(feat, featH, n * IN_F / 8);
    prepW_kernel<<<(NCOL * IN_F + 255) / 256, 256, 0, stream>>>(Wq, Wk, Wv, WT);
    mfma_proj_kernel<<<(n + 127) / 128, 256, 0, stream>>>(
        featH, WT, (unsigned short*)qk32, fth, n);
    hist_kernel<<<(nE + 255) / 256, 256, 0, stream>>>(dst, cnt, nE);
    scanA_kernel<<<NB, 256, 0, stream>>>(cnt, blocksum, n);
    scanB_kernel<<<1, 256, 0, stream>>>(blocksum, blockoff, rowptr, NB, n);
    scanC_kernel<<<NB, 256, 0, stream>>>(cnt, blockoff, rowptr, cursor, n);
    perm_kernel<<<(nE + 255) / 256, 256, 0, stream>>>(src, dst, bond, cursor,
                                                      srcs, bond_s, nE);
    agg_kernel<<<2048, 256, 0, stream>>>(rowptr, srcs, bond_s, qk32, fth,
                                         Wek, bek, Wef, bef, bias, out, n);
}